// Round 1
// baseline (222.759 us; speedup 1.0000x reference)
//
#include <hip/hip_runtime.h>

// Output: (1,3,4096,4096) fp32. All zeros except two 7x7 stamps per channel.
//
// Kernel 1: grid-stride float4 zero-fill of the whole output (harness poisons
//           d_out with 0xAA before every timed launch).
// Kernel 2: one small kernel computing the 2 stamps x 3 channels x lw*lw taps
//           with the reference's exact fp32 arithmetic.

__global__ void zero_fill_kernel(float4* __restrict__ out, long n4) {
    long i = blockIdx.x * (long)blockDim.x + threadIdx.x;
    long stride = (long)gridDim.x * blockDim.x;
    float4 z = make_float4(0.f, 0.f, 0.f, 0.f);
    for (; i < n4; i += stride) out[i] = z;
}

__global__ void stamp_kernel(const float* __restrict__ x0, const float* __restrict__ y0,
                             const float* __restrict__ x1, const float* __restrict__ y1,
                             const int* __restrict__ p_x0, const int* __restrict__ p_y0,
                             const int* __restrict__ p_x1, const int* __restrict__ p_y1,
                             const int* __restrict__ p_nsteps, const int* __restrict__ p_steep,
                             const int* __restrict__ p_imsize, const int* __restrict__ p_lw,
                             float* __restrict__ out) {
    const int lw = *p_lw;            // 7
    const int pad = lw / 2;          // 3
    const int imsize = *p_imsize;    // 4096
    const int steep = *p_steep;      // 0
    const float nsteps = (float)*p_nsteps;  // 3800

    // Stamp centers per reference: (r0,c0) = (_y0,_x0) if steep else (_x0,_y0);
    // stamp1 at (_x1,_y1).
    const int r0 = steep ? *p_y0 : *p_x0;
    const int c0 = steep ? *p_x0 : *p_y0;
    const int r1 = *p_x1;
    const int c1 = *p_y1;

    // v = z * (1/z) replicated bit-faithfully in fp32.
    const float z0 = x0[0] + y0[0];
    const float v0 = z0 * (1.0f / z0);
    const float z1 = x1[0] + y1[0];
    const float v1 = z1 * (1.0f / z1);

    const float inv = 1.0f / (float)(pad + 1);  // 0.25 for lw=7

    const int taps = lw * lw;        // 49
    const int total = taps * 3;      // 147 (3 channels)
    const int t = threadIdx.x;
    if (t >= total) return;

    const int s = blockIdx.x;        // which stamp (0 or 1)
    const int tap = t % taps;
    const int ch = t / taps;
    const int di = tap / lw - pad;
    const int dj = tap % lw - pad;

    const int r = (s == 0 ? r0 : r1) + di;
    const int c = (s == 0 ? c0 : c1) + dj;
    if (r < 0 || r >= imsize || c < 0 || c >= imsize) return;

    // Nested-square kernel value at offset (dr,dc) from a stamp center;
    // 0 outside the lw x lw footprint.
    auto kval = [&](int dr, int dc) -> float {
        int i = dr + pad, j = dc + pad;
        if (i < 0 || i >= lw || j < 0 || j >= lw) return 0.0f;
        int ring = min(min(i, j), min(lw - 1 - i, lw - 1 - j));
        return inv * (float)(ring + 1);
    };

    // Both blobs' contributions at this pixel (idempotent under overlap).
    const float k0 = kval(r - r0, c - c0);
    const float k1 = kval(r - r1, c - c1);
    float val = nsteps * (v0 * k0) + (v1 * k1);
    val = fminf(fmaxf(val, 0.0f), 1.0f);

    const size_t plane = (size_t)imsize * (size_t)imsize;
    out[(size_t)ch * plane + (size_t)r * (size_t)imsize + (size_t)c] = val;
}

extern "C" void kernel_launch(void* const* d_in, const int* in_sizes, int n_in,
                              void* d_out, int out_size, void* d_ws, size_t ws_size,
                              hipStream_t stream) {
    float* out = (float*)d_out;

    // 1) Zero the full output: out_size = 3*4096*4096 floats = 12,582,912 float4s.
    long n4 = (long)out_size / 4;
    const int threads = 256;
    const int blocks = 2048;  // 256 CUs x 8 blocks; grid-stride covers the rest
    zero_fill_kernel<<<blocks, threads, 0, stream>>>((float4*)out, n4);

    // Tail (out_size not divisible by 4) — not needed here but keep it exact.
    // (3*4096*4096 % 4 == 0, so no tail kernel required.)

    // 2) Stamp the two 7x7 blobs on all 3 channels.
    stamp_kernel<<<2, 256, 0, stream>>>(
        (const float*)d_in[0], (const float*)d_in[1],
        (const float*)d_in[2], (const float*)d_in[3],
        (const int*)d_in[4], (const int*)d_in[5],
        (const int*)d_in[6], (const int*)d_in[7],
        (const int*)d_in[8], (const int*)d_in[9],
        (const int*)d_in[10], (const int*)d_in[11],
        out);
}

// Round 2
// 212.269 us; speedup vs baseline: 1.0494x; 1.0494x over previous
//
#include <hip/hip_runtime.h>

// Output: (1,3,4096,4096) fp32. All zeros except two 7x7 stamps per channel.
//
// Step 1: hipMemsetAsync(d_out, 0) — lowers to rocclr fillBufferAligned,
//         measured at 6.7-6.8 TB/s on this chip (vs ~2 TB/s for the previous
//         hand-rolled grid-stride fill, inferred from the 100 us timing gap).
// Step 2: tiny stamp kernel computing the 2 stamps x 3 channels x 49 taps
//         with the reference's exact fp32 arithmetic.

__global__ void stamp_kernel(const float* __restrict__ x0, const float* __restrict__ y0,
                             const float* __restrict__ x1, const float* __restrict__ y1,
                             const int* __restrict__ p_x0, const int* __restrict__ p_y0,
                             const int* __restrict__ p_x1, const int* __restrict__ p_y1,
                             const int* __restrict__ p_nsteps, const int* __restrict__ p_steep,
                             const int* __restrict__ p_imsize, const int* __restrict__ p_lw,
                             float* __restrict__ out) {
    const int lw = *p_lw;            // 7
    const int pad = lw / 2;          // 3
    const int imsize = *p_imsize;    // 4096
    const int steep = *p_steep;      // 0
    const float nsteps = (float)*p_nsteps;  // 3800

    // Stamp centers per reference: (r0,c0) = (_y0,_x0) if steep else (_x0,_y0);
    // stamp1 at (_x1,_y1).
    const int r0 = steep ? *p_y0 : *p_x0;
    const int c0 = steep ? *p_x0 : *p_y0;
    const int r1 = *p_x1;
    const int c1 = *p_y1;

    // v = z * (1/z) replicated bit-faithfully in fp32.
    const float z0 = x0[0] + y0[0];
    const float v0 = z0 * (1.0f / z0);
    const float z1 = x1[0] + y1[0];
    const float v1 = z1 * (1.0f / z1);

    const float inv = 1.0f / (float)(pad + 1);  // 0.25 for lw=7

    const int taps = lw * lw;        // 49
    const int total = taps * 3;      // 147 (3 channels)
    const int t = threadIdx.x;
    if (t >= total) return;

    const int s = blockIdx.x;        // which stamp (0 or 1)
    const int tap = t % taps;
    const int ch = t / taps;
    const int di = tap / lw - pad;
    const int dj = tap % lw - pad;

    const int r = (s == 0 ? r0 : r1) + di;
    const int c = (s == 0 ? c0 : c1) + dj;
    if (r < 0 || r >= imsize || c < 0 || c >= imsize) return;

    // Nested-square kernel value at offset (dr,dc) from a stamp center;
    // 0 outside the lw x lw footprint.
    auto kval = [&](int dr, int dc) -> float {
        int i = dr + pad, j = dc + pad;
        if (i < 0 || i >= lw || j < 0 || j >= lw) return 0.0f;
        int ring = min(min(i, j), min(lw - 1 - i, lw - 1 - j));
        return inv * (float)(ring + 1);
    };

    // Both blobs' contributions at this pixel (idempotent under overlap).
    const float k0 = kval(r - r0, c - c0);
    const float k1 = kval(r - r1, c - c1);
    float val = nsteps * (v0 * k0) + (v1 * k1);
    val = fminf(fmaxf(val, 0.0f), 1.0f);

    const size_t plane = (size_t)imsize * (size_t)imsize;
    out[(size_t)ch * plane + (size_t)r * (size_t)imsize + (size_t)c] = val;
}

extern "C" void kernel_launch(void* const* d_in, const int* in_sizes, int n_in,
                              void* d_out, int out_size, void* d_ws, size_t ws_size,
                              hipStream_t stream) {
    float* out = (float*)d_out;

    // 1) Zero the full output via the tuned rocclr fill path (graph-capturable).
    hipMemsetAsync(out, 0, (size_t)out_size * sizeof(float), stream);

    // 2) Stamp the two 7x7 blobs on all 3 channels.
    stamp_kernel<<<2, 256, 0, stream>>>(
        (const float*)d_in[0], (const float*)d_in[1],
        (const float*)d_in[2], (const float*)d_in[3],
        (const int*)d_in[4], (const int*)d_in[5],
        (const int*)d_in[6], (const int*)d_in[7],
        (const int*)d_in[8], (const int*)d_in[9],
        (const int*)d_in[10], (const int*)d_in[11],
        out);
}